// Round 19
// baseline (473.245 us; speedup 1.0000x reference)
//
#include <hip/hip_runtime.h>
#include <hip/hip_bf16.h>

#define BB 4
#define TT 2048
#define DD 256
#define HH 4
#define HDD 64
#define NROW 8192   // B*T
#define NQ 128      // MAX_BITS*2

typedef __hip_bfloat16 bf16;
typedef __attribute__((ext_vector_type(8))) short bf8v;   // 8 bf16 = 4 VGPR
typedef __attribute__((ext_vector_type(4))) short bf4v;   // 4 bf16 = 2 VGPR
typedef __attribute__((ext_vector_type(4))) float f4v;

__device__ __forceinline__ bf16 f2b(float v){ return __float2bfloat16(v); }
__device__ __forceinline__ short f2bs(float v){
    bf16 h = __float2bfloat16(v);
    return *reinterpret_cast<short*>(&h);
}
__device__ __forceinline__ float bs2f(short s){
    bf16 h = *reinterpret_cast<bf16*>(&s);
    return __bfloat162float(h);
}
__device__ __forceinline__ float rl(float v, int l){
    return __uint_as_float(__builtin_amdgcn_readlane(__float_as_uint(v), l));
}

#define MFMA32(A,B,C) __builtin_amdgcn_mfma_f32_16x16x32_bf16((A),(B),(C),0,0,0)
#if __has_builtin(__builtin_amdgcn_mfma_f32_16x16x16bf16_1k)
#define MFMA16(A,B,C) __builtin_amdgcn_mfma_f32_16x16x16bf16_1k((A),(B),(C),0,0,0)
#else
__device__ __forceinline__ f4v mfma16_asm(bf4v a, bf4v b, f4v c){
    f4v d;
    asm("v_mfma_f32_16x16x16_bf16 %0, %1, %2, %3" : "=v"(d) : "v"(a), "v"(b), "v"(c));
    return d;
}
#define MFMA16(A,B,C) mfma16_asm((A),(B),(C))
#endif

// ---------------- fused embed + layer-0 LN1 ----------------
__global__ __launch_bounds__(256) void k_embln(const int* __restrict__ tok,
                                               const float* __restrict__ emb,
                                               const float* __restrict__ w,
                                               const float* __restrict__ b,
                                               float* __restrict__ x,
                                               bf16* __restrict__ Y){
    __shared__ float red[256];
    int n = blockIdx.x, d = threadIdx.x;
    float v = emb[(long)tok[n]*DD + d];
    x[(long)n*DD + d] = v;
    red[d] = v; __syncthreads();
    for (int s=128; s>0; s>>=1){ if (d<s) red[d]+=red[d+s]; __syncthreads(); }
    float mu = red[0] * (1.0f/DD); __syncthreads();
    float df = v - mu;
    red[d] = df*df; __syncthreads();
    for (int s=128; s>0; s>>=1){ if (d<s) red[d]+=red[d+s]; __syncthreads(); }
    float var = red[0] * (1.0f/DD);
    Y[(long)n*DD + d] = f2b(df*rsqrtf(var+1e-5f)*w[d] + b[d]);
}

// ---------------- prologue misc: trig tables + oq cast + w2 transpose ----------------
__global__ __launch_bounds__(256) void k_misc(const float* __restrict__ oq, bf16* __restrict__ oqb,
                                              float* __restrict__ cosT, float* __restrict__ sinT,
                                              const float* __restrict__ w2, float* __restrict__ w2t){
    int gid = blockIdx.x*256 + threadIdx.x;   // 65536 threads
    {
        int t = gid >> 5, dd = gid & 31;
        float invf = powf(10000.0f, -(float)(2*dd)/64.0f);
        float ang = (float)t * invf;
        float sn, cs;
        sincosf(ang, &sn, &cs);
        cosT[gid] = cs; sinT[gid] = sn;
    }
    if (gid < NQ*DD) oqb[gid] = f2b(oq[gid]);
    if (gid < 4096){ int j = gid >> 6, k = gid & 63; w2t[gid] = w2[k*64 + j]; }
}

// ---------------- all 8 weight cast+transposes in ONE dispatch ----------------
__global__ __launch_bounds__(256) void k_wtall(const float* __restrict__ qkvw,
                                               const float* __restrict__ projw,
                                               const float* __restrict__ f1w,
                                               const float* __restrict__ f2w,
                                               bf16* __restrict__ wt){
    __shared__ float t[32][33];
    int z = blockIdx.z;
    int l = z >> 2, type = z & 3;
    long L = (long)l*786432;
    int K, M; const float* src; long doff;
    if (type == 0){ K=256;  M=768;  src = qkvw + (long)l*256*768;  doff = L; }
    else if (type == 1){ K=256;  M=256;  src = projw + (long)l*256*256; doff = L + 196608; }
    else if (type == 2){ K=256;  M=1024; src = f1w  + (long)l*256*1024; doff = L + 262144; }
    else               { K=1024; M=256;  src = f2w  + (long)l*1024*256; doff = L + 524288; }
    int m0 = blockIdx.x*32, k0 = blockIdx.y*32;
    if (m0 >= M || k0 >= K) return;
    bf16* dst = wt + doff;
    int tx = threadIdx.x, ty = threadIdx.y;     // 32 x 8
    #pragma unroll
    for (int i=0;i<4;i++)
        t[ty+i*8][tx] = src[(long)(k0+ty+i*8)*M + m0 + tx];
    __syncthreads();
    #pragma unroll
    for (int i=0;i<4;i++)
        dst[(long)(m0+ty+i*8)*K + k0 + tx] = f2b(t[tx][ty+i*8]);
}

// ---------------- layernorm, bf16 out ----------------
__global__ __launch_bounds__(256) void k_lnb(const float* __restrict__ X,
                                             const float* __restrict__ w,
                                             const float* __restrict__ b,
                                             bf16* __restrict__ Y){
    __shared__ float red[256];
    int n = blockIdx.x, d = threadIdx.x;
    float v = X[(long)n*DD + d];
    red[d] = v; __syncthreads();
    for (int s=128; s>0; s>>=1){ if (d<s) red[d]+=red[d+s]; __syncthreads(); }
    float mu = red[0] * (1.0f/DD); __syncthreads();
    float df = v - mu;
    red[d] = df*df; __syncthreads();
    for (int s=128; s>0; s>>=1){ if (d<s) red[d]+=red[d+s]; __syncthreads(); }
    float var = red[0] * (1.0f/DD);
    Y[(long)n*DD + d] = f2b(df*rsqrtf(var+1e-5f)*w[d] + b[d]);
}

// ---------------- final layernorm: bf16 out + g[n] = y . ow ----------------
__global__ __launch_bounds__(256) void k_lnf(const float* __restrict__ X,
                                             const float* __restrict__ w,
                                             const float* __restrict__ b,
                                             const float* __restrict__ ow,
                                             bf16* __restrict__ Yb,
                                             float* __restrict__ g){
    __shared__ float red[256];
    int n = blockIdx.x, d = threadIdx.x;
    float v = X[(long)n*DD + d];
    red[d] = v; __syncthreads();
    for (int s=128; s>0; s>>=1){ if (d<s) red[d]+=red[d+s]; __syncthreads(); }
    float mu = red[0] * (1.0f/DD); __syncthreads();
    float df = v - mu;
    red[d] = df*df; __syncthreads();
    for (int s=128; s>0; s>>=1){ if (d<s) red[d]+=red[d+s]; __syncthreads(); }
    float var = red[0] * (1.0f/DD);
    float y = df*rsqrtf(var+1e-5f)*w[d] + b[d];
    Yb[(long)n*DD + d] = f2b(y);
    __syncthreads();
    red[d] = y * ow[d]; __syncthreads();
    for (int s=128; s>0; s>>=1){ if (d<s) red[d]+=red[d+s]; __syncthreads(); }
    if (d == 0) g[n] = red[0];
}

// ---------------- MFMA GEMM: C[N,M] = A[N,K](bf16) @ Wt[M,K](bf16)^T + bias ----------------
// mode 0: Cf = v ; mode 1: Cf += v ; mode 2: Cb = gelu(v) ; mode 3: Cb = v
__global__ __launch_bounds__(256) void k_mgemm(const bf16* __restrict__ A,
                                               const bf16* __restrict__ Wt,
                                               const float* __restrict__ bias,
                                               float* __restrict__ Cf,
                                               bf16* __restrict__ Cb,
                                               int K, int M, int mode){
    __shared__ short As[128*32];
    __shared__ short Ws[64*32];
    int tid = threadIdx.x;
    int lane = tid & 63, wv = tid >> 6;
    int n0 = blockIdx.y * 128, m0 = blockIdx.x * 64;
    int rbase = (wv >> 1) * 64, cbase = (wv & 1) * 32;
    f4v acc[4][2] = {};
    int s2 = tid + 256;
    for (int k0 = 0; k0 < K; k0 += 32){
        bf8v va0 = *(const bf8v*)(A  + (long)(n0 + (tid>>2))*K + k0 + ((tid&3)<<3));
        bf8v va1 = *(const bf8v*)(A  + (long)(n0 + (s2 >>2))*K + k0 + ((s2 &3)<<3));
        bf8v vw  = *(const bf8v*)(Wt + (long)(m0 + (tid>>2))*K + k0 + ((tid&3)<<3));
        __syncthreads();
        *(bf8v*)&As[tid*8] = va0;
        *(bf8v*)&As[s2 *8] = va1;
        *(bf8v*)&Ws[tid*8] = vw;
        __syncthreads();
        bf8v af[4], bfr[2];
        int k8 = (lane >> 4) << 3;
        #pragma unroll
        for (int i=0;i<4;i++) af[i]  = *(bf8v*)&As[(rbase + i*16 + (lane&15))*32 + k8];
        #pragma unroll
        for (int j=0;j<2;j++) bfr[j] = *(bf8v*)&Ws[(cbase + j*16 + (lane&15))*32 + k8];
        #pragma unroll
        for (int i=0;i<4;i++)
            #pragma unroll
            for (int j=0;j<2;j++)
                acc[i][j] = MFMA32(af[i], bfr[j], acc[i][j]);
    }
    int rq = (lane >> 4) * 4;
    int cl = lane & 15;
    #pragma unroll
    for (int i=0;i<4;i++){
        #pragma unroll
        for (int j=0;j<2;j++){
            int m = m0 + cbase + j*16 + cl;
            float bs = bias[m];
            #pragma unroll
            for (int r=0;r<4;r++){
                int n = n0 + rbase + i*16 + rq + r;
                float v = acc[i][j][r] + bs;
                long idx = (long)n*M + m;
                if (mode == 0)      Cf[idx] = v;
                else if (mode == 1) Cf[idx] += v;
                else if (mode == 2) Cb[idx] = f2b(0.5f*v*(1.0f + erff(v*0.70710678118654752f)));
                else                Cb[idx] = f2b(v);
            }
        }
    }
}

// ---------------- fused QKV GEMM + bias + RoPE + V tile-transpose ----------------
__global__ __launch_bounds__(256) void k_mgemmQKV(const bf16* __restrict__ A,
                                                  const bf16* __restrict__ Wt,
                                                  const float* __restrict__ bias,
                                                  const float* __restrict__ cosT,
                                                  const float* __restrict__ sinT,
                                                  bf16* __restrict__ qb,
                                                  bf16* __restrict__ kb,
                                                  bf16* __restrict__ vt){
    __shared__ short As[128*32];
    __shared__ short Ws[64*32];
    __shared__ short E[128][68];
    const int K = 256, M = 768;
    int tid = threadIdx.x;
    int lane = tid & 63, wv = tid >> 6;
    int n0 = blockIdx.y * 128, m0 = blockIdx.x * 64;
    int rbase = (wv >> 1) * 64, cbase = (wv & 1) * 32;
    f4v acc[4][2] = {};
    int s2 = tid + 256;
    for (int k0 = 0; k0 < K; k0 += 32){
        bf8v va0 = *(const bf8v*)(A  + (long)(n0 + (tid>>2))*K + k0 + ((tid&3)<<3));
        bf8v va1 = *(const bf8v*)(A  + (long)(n0 + (s2 >>2))*K + k0 + ((s2 &3)<<3));
        bf8v vw  = *(const bf8v*)(Wt + (long)(m0 + (tid>>2))*K + k0 + ((tid&3)<<3));
        __syncthreads();
        *(bf8v*)&As[tid*8] = va0;
        *(bf8v*)&As[s2 *8] = va1;
        *(bf8v*)&Ws[tid*8] = vw;
        __syncthreads();
        bf8v af[4], bfr[2];
        int k8 = (lane >> 4) << 3;
        #pragma unroll
        for (int i=0;i<4;i++) af[i]  = *(bf8v*)&As[(rbase + i*16 + (lane&15))*32 + k8];
        #pragma unroll
        for (int j=0;j<2;j++) bfr[j] = *(bf8v*)&Ws[(cbase + j*16 + (lane&15))*32 + k8];
        #pragma unroll
        for (int i=0;i<4;i++)
            #pragma unroll
            for (int j=0;j<2;j++)
                acc[i][j] = MFMA32(af[i], bfr[j], acc[i][j]);
    }
    int rq = (lane >> 4) * 4;
    int cl = lane & 15;
    #pragma unroll
    for (int i=0;i<4;i++){
        #pragma unroll
        for (int j=0;j<2;j++){
            int cc = cbase + j*16 + cl;
            float bs = bias[m0 + cc];
            #pragma unroll
            for (int r=0;r<4;r++)
                E[rbase + i*16 + rq + r][cc] = f2bs(acc[i][j][r] + bs);
        }
    }
    __syncthreads();
    int part = m0 >> 8;
    int h = (m0 >> 6) & 3;
    int b = n0 >> 11;
    int t0 = n0 & 2047;
    int bh = b*HH + h;
    if (part < 2){
        bf16* dst0 = part ? kb : qb;
        int r2 = tid >> 2;
        int c0 = (tid & 3) * 16;
        int cpx = c0 ^ 32;
        #pragma unroll
        for (int half=0; half<2; half++){
            int row = half*64 + r2;
            int t = t0 + row;
            bf8v e0 = *(bf8v*)&E[row][c0];
            bf8v e1 = *(bf8v*)&E[row][c0+8];
            bf8v p0 = *(bf8v*)&E[row][cpx];
            bf8v p1 = *(bf8v*)&E[row][cpx+8];
            const float* ct = cosT + t*32;
            const float* st = sinT + t*32;
            short o[16];
            #pragma unroll
            for (int i=0;i<8;i++){
                int d = c0 + i, dd = d & 31;
                float cs = ct[dd], sn = st[dd];
                float v = bs2f(e0[i]), v2 = bs2f(p0[i]);
                o[i] = f2bs((d < 32) ? (v*cs - v2*sn) : (v*cs + v2*sn));
            }
            #pragma unroll
            for (int i=0;i<8;i++){
                int d = c0 + 8 + i, dd = d & 31;
                float cs = ct[dd], sn = st[dd];
                float v = bs2f(e1[i]), v2 = bs2f(p1[i]);
                o[8+i] = f2bs((d < 32) ? (v*cs - v2*sn) : (v*cs + v2*sn));
            }
            short* dp = (short*)dst0 + ((long)bh*TT + t)*64 + c0;
            *(bf8v*)dp     = *(bf8v*)&o[0];
            *(bf8v*)(dp+8) = *(bf8v*)&o[8];
        }
    } else {
        int tIdx0 = t0 >> 6;
        int d  = (tid & 127) >> 1;
        int k0 = (tid & 1) * 32;
        int tt = tid >> 7;
        short o[32];
        #pragma unroll
        for (int k=0;k<32;k++) o[k] = E[tt*64 + k0 + k][d];
        short* dp = (short*)vt + (((long)bh*32 + tIdx0 + tt)*64 + d)*64 + k0;
        *(bf8v*)dp      = *(bf8v*)&o[0];
        *(bf8v*)(dp+8)  = *(bf8v*)&o[8];
        *(bf8v*)(dp+16) = *(bf8v*)&o[16];
        *(bf8v*)(dp+24) = *(bf8v*)&o[24];
    }
}

// ---------------- MFMA flash attention: SPLIT-K over keys + LDS-staged dbuf tiles ----------------
// grid (32*4, BH): x = qt*4 + chunk c; chunk = up to 8 key-tiles. Unnormalized
// partial O (bf16) + row-sums (fp32); plain summation combine (no max-sub, |s|<~1).
// Staged, double-buffered LDS (the R9 split-K failure was direct global fragment
// loads; staging is the R11 fix). ~5 active blocks/CU for latency hiding.
__global__ __launch_bounds__(256) void k_fattn(const bf16* __restrict__ qb,
                                               const bf16* __restrict__ kb,
                                               const bf16* __restrict__ vt,
                                               bf16* __restrict__ PO,
                                               float* __restrict__ PL){
    __shared__ short Ks[2][64][72];
    __shared__ short Vs[2][64][68];
    int xq = blockIdx.x;
    int qt = xq >> 2, c = xq & 3;
    int nc = (qt + 8) >> 3;                  // ceil((qt+1)/8)
    if (c >= nc) return;
    int bh = blockIdx.y;
    int tid = threadIdx.x;
    int lane = tid & 63, w = tid >> 6;
    int col = lane & 15, quad = lane >> 4;
    int q0 = qt*64 + w*16;
    const bf16* qp = qb + ((long)bh*TT + q0 + col)*64 + quad*8;
    bf8v bq0 = *(const bf8v*)(qp);
    bf8v bq1 = *(const bf8v*)(qp + 32);
    f4v oc[4] = {};
    float lsum = 0.f;
    int qglob = q0 + col;
    int srow = tid >> 2, sc0 = (tid & 3) * 16;
    const short* kgb = (const short*)kb + ((long)bh*TT + srow)*64 + sc0;
    const short* vgb = (const short*)vt + (((long)bh*32)*64 + srow)*64 + sc0;

    int kt0 = c*8, kt1 = min(kt0 + 8, qt + 1);
    // prologue: tile kt0 -> buf 0
    bf8v pk0 = *(const bf8v*)(kgb + (long)kt0*4096);
    bf8v pk1 = *(const bf8v*)(kgb + (long)kt0*4096 + 8);
    bf8v pv0 = *(const bf8v*)(vgb + (long)kt0*4096);
    bf8v pv1 = *(const bf8v*)(vgb + (long)kt0*4096 + 8);
    *(bf8v*)&Ks[0][srow][sc0]     = pk0;
    *(bf8v*)&Ks[0][srow][sc0 + 8] = pk1;
    *(bf8v*)&Vs[0][srow][sc0]     = pv0;
    *(bf8v*)&Vs[0][srow][sc0 + 8] = pv1;

    int buf = 0;
    for (int kt=kt0; kt<kt1; kt++){
        __syncthreads();
        bool more = (kt + 1 < kt1);
        if (more){
            const short* kg = kgb + (long)(kt+1)*4096;
            const short* vg = vgb + (long)(kt+1)*4096;
            pk0 = *(const bf8v*)kg;
            pk1 = *(const bf8v*)(kg + 8);
            pv0 = *(const bf8v*)vg;
            pv1 = *(const bf8v*)(vg + 8);
        }
        bool diag = (kt == qt);
        int ntmax = diag ? w : 3;
        bf4v bp[4];
        #pragma unroll
        for (int nt=0; nt<4; nt++){
            if (nt > ntmax) continue;
            bf8v ka0 = *(const bf8v*)&Ks[buf][nt*16 + col][quad*8];
            bf8v ka1 = *(const bf8v*)&Ks[buf][nt*16 + col][32 + quad*8];
            f4v st = {};
            st = MFMA32(ka0, bq0, st);
            st = MFMA32(ka1, bq1, st);
            int key0 = kt*64 + nt*16 + quad*4;
            bf4v pb;
            #pragma unroll
            for (int r=0; r<4; r++){
                float e = __expf(st[r]*0.125f);
                if (diag && (key0 + r > qglob)) e = 0.f;
                lsum += e;
                pb[r] = f2bs(e);
            }
            bp[nt] = pb;
        }
        #pragma unroll
        for (int dt=0; dt<4; dt++){
            #pragma unroll
            for (int nt=0; nt<4; nt++){
                if (nt > ntmax) continue;
                bf4v va = *(const bf4v*)&Vs[buf][dt*16 + col][nt*16 + quad*4];
                oc[dt] = MFMA16(va, bp[nt], oc[dt]);
            }
        }
        if (more){
            *(bf8v*)&Ks[buf^1][srow][sc0]     = pk0;
            *(bf8v*)&Ks[buf^1][srow][sc0 + 8] = pk1;
            *(bf8v*)&Vs[buf^1][srow][sc0]     = pv0;
            *(bf8v*)&Vs[buf^1][srow][sc0 + 8] = pv1;
        }
        buf ^= 1;
    }
    // per-q row-sum across quads (every lane ends with q=col's sum)
    lsum += __shfl_xor(lsum, 16, 64);
    lsum += __shfl_xor(lsum, 32, 64);

    long idx = ((long)bh*32 + qt)*4 + c;
    short* pod = (short*)PO + idx*4096 + (w*16 + col)*64 + quad*4;
    #pragma unroll
    for (int dt=0; dt<4; dt++){
        bf4v o4;
        #pragma unroll
        for (int r=0; r<4; r++) o4[r] = f2bs(oc[dt][r]);
        *(bf4v*)(pod + dt*16) = o4;
    }
    if (quad == 0) PL[idx*64 + w*16 + col] = lsum;
}

// ---------------- combine split-K partials -> attnb [b][t][h*64+d] ----------------
__global__ __launch_bounds__(256) void k_acomb(const bf16* __restrict__ PO,
                                               const float* __restrict__ PL,
                                               bf16* __restrict__ ob){
    int qt = blockIdx.x, bh = blockIdx.y;
    int nc = (qt + 8) >> 3;
    int tid = threadIdx.x;
    int q = tid >> 2, dg = (tid & 3) * 16;
    long base = ((long)bh*32 + qt)*4;
    float l = 0.f;
    float acc[16] = {};
    for (int c=0; c<nc; c++){
        l += PL[(base + c)*64 + q];
        const short* ps = (const short*)PO + (base + c)*4096 + q*64 + dg;
        bf8v v0 = *(const bf8v*)ps;
        bf8v v1 = *(const bf8v*)(ps + 8);
        #pragma unroll
        for (int i=0;i<8;i++) acc[i]   += bs2f(v0[i]);
        #pragma unroll
        for (int i=0;i<8;i++) acc[8+i] += bs2f(v1[i]);
    }
    float linv = 1.0f / l;
    int b = bh / HH, h = bh % HH;
    short* dst = (short*)ob + ((long)b*TT + qt*64 + q)*DD + h*64 + dg;
    bf8v o0, o1;
    #pragma unroll
    for (int i=0;i<8;i++) o0[i] = f2bs(acc[i]*linv);
    #pragma unroll
    for (int i=0;i<8;i++) o1[i] = f2bs(acc[8+i]*linv);
    *(bf8v*)dst = o0;
    *(bf8v*)(dst + 8) = o1;
}

// ---------------- pooling scores: S[b][q][t] = (oq[q] . xf[b,t]) / 16, MFMA ----------------
__global__ __launch_bounds__(256) void k_score(const bf16* __restrict__ oqb,
                                               const bf16* __restrict__ xfb,
                                               float* __restrict__ S){
    int b = blockIdx.y, t0 = blockIdx.x*64;
    int tid = threadIdx.x, lane = tid & 63, w = tid >> 6;
    int col = lane & 15, quad = lane >> 4, k8 = quad << 3;
    const bf16* xb = xfb + (long)b*TT*DD;
    f4v acc[2][4] = {};
    #pragma unroll
    for (int ko=0; ko<8; ko++){
        int kk = ko*32 + k8;
        bf8v a0 = *(const bf8v*)(oqb + (long)(w*32 +      col)*DD + kk);
        bf8v a1 = *(const bf8v*)(oqb + (long)(w*32 + 16 + col)*DD + kk);
        #pragma unroll
        for (int bt=0; bt<4; bt++){
            bf8v bv = *(const bf8v*)(xb + (long)(t0 + bt*16 + col)*DD + kk);
            acc[0][bt] = MFMA32(a0, bv, acc[0][bt]);
            acc[1][bt] = MFMA32(a1, bv, acc[1][bt]);
        }
    }
    #pragma unroll
    for (int qt2=0; qt2<2; qt2++){
        #pragma unroll
        for (int bt=0; bt<4; bt++){
            #pragma unroll
            for (int r=0; r<4; r++){
                int q = w*32 + qt2*16 + quad*4 + r;
                S[((long)b*NQ + q)*TT + t0 + bt*16 + col] = acc[qt2][bt][r]*0.0625f;
            }
        }
    }
}

// ---------------- softmax row + fused bit: one (b,q) per block ----------------
__global__ __launch_bounds__(256) void k_psoft(const float* __restrict__ S,
                                               const float* __restrict__ g,
                                               const float* __restrict__ obias,
                                               float* __restrict__ out_qattn,
                                               float* __restrict__ out_pairs,
                                               float* __restrict__ bits){
    __shared__ float p[TT];
    __shared__ float red[256];
    int bq = blockIdx.x, b = bq >> 7;
    int tid = threadIdx.x;
    const float* Srow = S + (long)bq*TT;
    float lmax = -1e30f;
    for (int t=tid; t<TT; t+=256){ float s = Srow[t]; p[t] = s; lmax = fmaxf(lmax, s); }
    red[tid] = lmax; __syncthreads();
    for (int s2=128; s2>0; s2>>=1){ if (tid<s2) red[tid]=fmaxf(red[tid],red[tid+s2]); __syncthreads(); }
    float m = red[0]; __syncthreads();
    const float* gb = g + (long)b*TT;
    float lsum = 0.f, gdot = 0.f;
    for (int t=tid; t<TT; t+=256){
        float e = __expf(p[t]-m); p[t] = e;
        lsum += e; gdot += e*gb[t];
    }
    red[tid] = lsum; __syncthreads();
    for (int s2=128; s2>0; s2>>=1){ if (tid<s2) red[tid]+=red[tid+s2]; __syncthreads(); }
    float inv = 1.0f/red[0]; __syncthreads();
    red[tid] = gdot; __syncthreads();
    for (int s2=128; s2>0; s2>>=1){ if (tid<s2) red[tid]+=red[tid+s2]; __syncthreads(); }
    float gsum = red[0];
    for (int t=tid; t<TT; t+=256) out_qattn[(long)bq*TT + t] = p[t]*inv;
    if (tid == 0){
        float bit = 1.0f/(1.0f + expf(-(gsum*inv + obias[0])));
        bits[bq] = bit;
        out_pairs[bq] = bit;
    }
}

// ---------------- sequential 64-step carry MLP (structural floor ~51 us) ----------------
__global__ __launch_bounds__(64) void k_scan(const float* __restrict__ bits,
                                             const float* __restrict__ w1, const float* __restrict__ b1,
                                             const float* __restrict__ w2t, const float* __restrict__ b2,
                                             const float* __restrict__ w3, const float* __restrict__ b3,
                                             float* __restrict__ out_sum){
    int b = blockIdx.x, lane = threadIdx.x;
    float w1c0 = w1[lane], w1c1 = w1[64 + lane], w1c2 = w1[128 + lane];
    float b1v = b1[lane], b2v = b2[lane];
    float w3c0 = w3[lane*2 + 0], w3c1 = w3[lane*2 + 1];
    float b30 = b3[0], b31 = b3[1];
    const f4v* wrow = (const f4v*)(w2t + (long)lane*64);
    f4v c0v = wrow[0],  c1v = wrow[1],  c2v = wrow[2],  c3v = wrow[3],
        c4v = wrow[4],  c5v = wrow[5],  c6v = wrow[6],  c7v = wrow[7],
        c8v = wrow[8],  c9v = wrow[9],  cav = wrow[10], cbv = wrow[11],
        ccv = wrow[12], cdv = wrow[13], cev = wrow[14], cfv = wrow[15];
    float z0v = bits[b*128 + lane*2 + 0];
    float z1v = bits[b*128 + lane*2 + 1];
    float carry = 0.f;
    for (int step=0; step<64; step++){
        float z0 = rl(z0v, step);
        float z1 = rl(z1v, step);
        float h1 = fmaxf(z0*w1c0 + z1*w1c1 + carry*w1c2 + b1v, 0.f);
        float a0 = b2v, a1 = 0.f, a2 = 0.f, a3 = 0.f;
#define MAC(i, c) { a0 += rl(h1, 4*i+0) * c[0]; a1 += rl(h1, 4*i+1) * c[1]; \
                    a2 += rl(h1, 4*i+2) * c[2]; a3 += rl(h1, 4*i+3) * c[3]; }
        MAC(0,c0v)  MAC(1,c1v)  MAC(2,c2v)  MAC(3,c3v)
        MAC(4,c4v)  MAC(5,c5v)  MAC(6,c6v)  MAC(7,c7v)
        MAC(8,c8v)  MAC(9,c9v)  MAC(10,cav) MAC(11,cbv)
        MAC(12,ccv) MAC(13,cdv) MAC(14,cev) MAC(15,cfv)
#undef MAC
        float h2 = fmaxf((a0+a1)+(a2+a3), 0.f);
        float t0 = h2*w3c0, t1 = h2*w3c1;
        #pragma unroll
        for (int m=1; m<64; m<<=1){
            t0 += __shfl_xor(t0, m, 64);
            t1 += __shfl_xor(t1, m, 64);
        }
        float o0 = 1.0f/(1.0f + __expf(-(t0 + b30)));
        carry    = 1.0f/(1.0f + __expf(-(t1 + b31)));
        if (lane == 0) out_sum[b*65 + step] = o0;
    }
    if (lane == 0) out_sum[b*65 + 64] = carry;
}

extern "C" void kernel_launch(void* const* d_in, const int* in_sizes, int n_in,
                              void* d_out, int out_size, void* d_ws, size_t ws_size,
                              hipStream_t stream){
    const int*   tok   = (const int*)d_in[0];
    const float* emb   = (const float*)d_in[1];
    const float* ln1w  = (const float*)d_in[2];
    const float* ln1b  = (const float*)d_in[3];
    const float* qkvw  = (const float*)d_in[4];
    const float* qkvb  = (const float*)d_in[5];
    const float* projw = (const float*)d_in[6];
    const float* projb = (const float*)d_in[7];
    const float* ln2w  = (const float*)d_in[8];
    const float* ln2b  = (const float*)d_in[9];
    const float* f1w   = (const float*)d_in[10];
    const float* f1b   = (const float*)d_in[11];
    const float* f2w   = (const float*)d_in[12];
    const float* f2bb  = (const float*)d_in[13];
    const float* lnfw  = (const float*)d_in[14];
    const float* lnfb  = (const float*)d_in[15];
    const float* oq    = (const float*)d_in[16];
    const float* ow    = (const float*)d_in[17];
    const float* obias = (const float*)d_in[18];
    const float* w1    = (const float*)d_in[19];
    const float* b1    = (const float*)d_in[20];
    const float* w2    = (const float*)d_in[21];
    const float* b2    = (const float*)d_in[22];
    const float* w3    = (const float*)d_in[23];
    const float* b3    = (const float*)d_in[24];
    float* out = (float*)d_out;

    const long MB = 1048576;
    char* W = (char*)d_ws;
    float* x     = (float*)(W);            // [0,8M) residual fp32
    bf16*  attnb = (bf16*)(W + 8*MB);      // [8M,12M)
    float* PL    = (float*)(W + 12*MB);    // [12M,12.5M) split-K row-sums
    bf16*  PO    = (bf16*)(W + 16*MB);     // [16M,32M) split-K partial O (time-disjoint with hb)
    bf16*  hb    = (bf16*)(W + 16*MB);     // [16M,32M) FFN hidden bf16
    bf16*  qb    = (bf16*)(W + 32*MB);     // [32M,36M)
    bf16*  kb    = (bf16*)(W + 36*MB);     // [36M,40M)
    bf16*  vt    = (bf16*)(W + 44*MB);     // [44M,48M) V tile-blocked [bh][kt][d][k]
    bf16*  xnb   = (bf16*)(W + 48*MB);     // [48M,52M) LN out bf16
    bf16*  wt    = (bf16*)(W + 52*MB);     // [52M,55M) weights bf16 K-major
    float* bits  = (float*)(W + 55*MB);    // 2 KB
    bf16*  oqb   = (bf16*)(W + 56*MB);     // 64 KB
    float* cosT  = (float*)(W + 57*MB);    // 256 KB
    float* sinT  = cosT + 65536;           // 256 KB
    float* w2t   = (float*)(W + 58*MB);    // 16 KB
    bf16*  xfb   = (bf16*)(W + 32*MB);     // final LN bf16 (aliases dead qb)
    float* g     = (float*)(W + 36*MB);    // 32 KB (aliases dead kb)
    float* S     = (float*)(W + 40*MB);    // [40M,44M) scores fp32
    // wt per-layer offsets (bf16 elems), layer stride 786432:
    //   qkvT +0 | projT +196608 | f1T +262144 | f2T +524288

    k_wtall<<<dim3(32, 32, 8), dim3(32,8), 0, stream>>>(qkvw, projw, f1w, f2w, wt);
    k_misc<<<256, 256, 0, stream>>>(oq, oqb, cosT, sinT, w2, w2t);

    k_embln<<<NROW, 256, 0, stream>>>(tok, emb, ln1w, ln1b, x, xnb);
    for (int l=0; l<2; l++){
        long L = (long)l*786432;
        if (l) k_lnb<<<NROW, 256, 0, stream>>>(x, ln1w + l*DD, ln1b + l*DD, xnb);
        k_mgemmQKV<<<dim3(768/64, 64), 256, 0, stream>>>(
            xnb, wt + L, qkvb + l*768, cosT, sinT, qb, kb, vt);
        k_fattn<<<dim3(32*4, BB*HH), 256, 0, stream>>>(qb, kb, vt, PO, PL);
        k_acomb<<<dim3(32, BB*HH), 256, 0, stream>>>(PO, PL, attnb);
        k_mgemm<<<dim3(256/64, 64), 256, 0, stream>>>(
            attnb, wt + L + 196608, projb + l*DD, x, (bf16*)0, 256, 256, 1);
        k_lnb<<<NROW, 256, 0, stream>>>(x, ln2w + l*DD, ln2b + l*DD, xnb);
        k_mgemm<<<dim3(1024/64, 64), 256, 0, stream>>>(
            xnb, wt + L + 262144, f1b + l*1024, (float*)0, hb, 256, 1024, 2);
        k_mgemm<<<dim3(256/64, 64), 256, 0, stream>>>(
            hb, wt + L + 524288, f2bb + l*DD, x, (bf16*)0, 1024, 256, 1);
    }
    k_lnf<<<NROW, 256, 0, stream>>>(x, lnfw, lnfb, ow, xfb, g);
    // outputs: sum_all [0,260) | pairs [260,772) | q_attn [772, 772+4*128*2048)
    k_score<<<dim3(TT/64, BB), 256, 0, stream>>>(oqb, xfb, S);
    k_psoft<<<BB*NQ, 256, 0, stream>>>(S, g, obias, out + 772, out + 260, bits);
    k_scan<<<4, 64, 0, stream>>>(bits, w1, b1, w2t, b2, w3, b3, out);
}

// Round 20
// 454.900 us; speedup vs baseline: 1.0403x; 1.0403x over previous
//
#include <hip/hip_runtime.h>
#include <hip/hip_bf16.h>

#define BB 4
#define TT 2048
#define DD 256
#define HH 4
#define HDD 64
#define NROW 8192   // B*T
#define NQ 128      // MAX_BITS*2

typedef __hip_bfloat16 bf16;
typedef __attribute__((ext_vector_type(8))) short bf8v;   // 8 bf16 = 4 VGPR
typedef __attribute__((ext_vector_type(4))) short bf4v;   // 4 bf16 = 2 VGPR
typedef __attribute__((ext_vector_type(4))) float f4v;

__device__ __forceinline__ bf16 f2b(float v){ return __float2bfloat16(v); }
__device__ __forceinline__ short f2bs(float v){
    bf16 h = __float2bfloat16(v);
    return *reinterpret_cast<short*>(&h);
}
__device__ __forceinline__ float bs2f(short s){
    bf16 h = *reinterpret_cast<bf16*>(&s);
    return __bfloat162float(h);
}
__device__ __forceinline__ float rl(float v, int l){
    return __uint_as_float(__builtin_amdgcn_readlane(__float_as_uint(v), l));
}

#define MFMA32(A,B,C) __builtin_amdgcn_mfma_f32_16x16x32_bf16((A),(B),(C),0,0,0)
#if __has_builtin(__builtin_amdgcn_mfma_f32_16x16x16bf16_1k)
#define MFMA16(A,B,C) __builtin_amdgcn_mfma_f32_16x16x16bf16_1k((A),(B),(C),0,0,0)
#else
__device__ __forceinline__ f4v mfma16_asm(bf4v a, bf4v b, f4v c){
    f4v d;
    asm("v_mfma_f32_16x16x16_bf16 %0, %1, %2, %3" : "=v"(d) : "v"(a), "v"(b), "v"(c));
    return d;
}
#define MFMA16(A,B,C) mfma16_asm((A),(B),(C))
#endif

// ---------------- fused embed + layer-0 LN1 ----------------
__global__ __launch_bounds__(256) void k_embln(const int* __restrict__ tok,
                                               const float* __restrict__ emb,
                                               const float* __restrict__ w,
                                               const float* __restrict__ b,
                                               float* __restrict__ x,
                                               bf16* __restrict__ Y){
    __shared__ float red[256];
    int n = blockIdx.x, d = threadIdx.x;
    float v = emb[(long)tok[n]*DD + d];
    x[(long)n*DD + d] = v;
    red[d] = v; __syncthreads();
    for (int s=128; s>0; s>>=1){ if (d<s) red[d]+=red[d+s]; __syncthreads(); }
    float mu = red[0] * (1.0f/DD); __syncthreads();
    float df = v - mu;
    red[d] = df*df; __syncthreads();
    for (int s=128; s>0; s>>=1){ if (d<s) red[d]+=red[d+s]; __syncthreads(); }
    float var = red[0] * (1.0f/DD);
    Y[(long)n*DD + d] = f2b(df*rsqrtf(var+1e-5f)*w[d] + b[d]);
}

// ---------------- prologue misc: trig tables + oq cast + w2 transpose ----------------
__global__ __launch_bounds__(256) void k_misc(const float* __restrict__ oq, bf16* __restrict__ oqb,
                                              float* __restrict__ cosT, float* __restrict__ sinT,
                                              const float* __restrict__ w2, float* __restrict__ w2t){
    int gid = blockIdx.x*256 + threadIdx.x;   // 65536 threads
    {
        int t = gid >> 5, dd = gid & 31;
        float invf = powf(10000.0f, -(float)(2*dd)/64.0f);
        float ang = (float)t * invf;
        float sn, cs;
        sincosf(ang, &sn, &cs);
        cosT[gid] = cs; sinT[gid] = sn;
    }
    if (gid < NQ*DD) oqb[gid] = f2b(oq[gid]);
    if (gid < 4096){ int j = gid >> 6, k = gid & 63; w2t[gid] = w2[k*64 + j]; }
}

// ---------------- all 8 weight cast+transposes in ONE dispatch ----------------
__global__ __launch_bounds__(256) void k_wtall(const float* __restrict__ qkvw,
                                               const float* __restrict__ projw,
                                               const float* __restrict__ f1w,
                                               const float* __restrict__ f2w,
                                               bf16* __restrict__ wt){
    __shared__ float t[32][33];
    int z = blockIdx.z;
    int l = z >> 2, type = z & 3;
    long L = (long)l*786432;
    int K, M; const float* src; long doff;
    if (type == 0){ K=256;  M=768;  src = qkvw + (long)l*256*768;  doff = L; }
    else if (type == 1){ K=256;  M=256;  src = projw + (long)l*256*256; doff = L + 196608; }
    else if (type == 2){ K=256;  M=1024; src = f1w  + (long)l*256*1024; doff = L + 262144; }
    else               { K=1024; M=256;  src = f2w  + (long)l*1024*256; doff = L + 524288; }
    int m0 = blockIdx.x*32, k0 = blockIdx.y*32;
    if (m0 >= M || k0 >= K) return;
    bf16* dst = wt + doff;
    int tx = threadIdx.x, ty = threadIdx.y;     // 32 x 8
    #pragma unroll
    for (int i=0;i<4;i++)
        t[ty+i*8][tx] = src[(long)(k0+ty+i*8)*M + m0 + tx];
    __syncthreads();
    #pragma unroll
    for (int i=0;i<4;i++)
        dst[(long)(m0+ty+i*8)*K + k0 + tx] = f2b(t[tx][ty+i*8]);
}

// ---------------- layernorm, bf16 out ----------------
__global__ __launch_bounds__(256) void k_lnb(const float* __restrict__ X,
                                             const float* __restrict__ w,
                                             const float* __restrict__ b,
                                             bf16* __restrict__ Y){
    __shared__ float red[256];
    int n = blockIdx.x, d = threadIdx.x;
    float v = X[(long)n*DD + d];
    red[d] = v; __syncthreads();
    for (int s=128; s>0; s>>=1){ if (d<s) red[d]+=red[d+s]; __syncthreads(); }
    float mu = red[0] * (1.0f/DD); __syncthreads();
    float df = v - mu;
    red[d] = df*df; __syncthreads();
    for (int s=128; s>0; s>>=1){ if (d<s) red[d]+=red[d+s]; __syncthreads(); }
    float var = red[0] * (1.0f/DD);
    Y[(long)n*DD + d] = f2b(df*rsqrtf(var+1e-5f)*w[d] + b[d]);
}

// ---------------- final layernorm: bf16 out + g[n] = y . ow ----------------
__global__ __launch_bounds__(256) void k_lnf(const float* __restrict__ X,
                                             const float* __restrict__ w,
                                             const float* __restrict__ b,
                                             const float* __restrict__ ow,
                                             bf16* __restrict__ Yb,
                                             float* __restrict__ g){
    __shared__ float red[256];
    int n = blockIdx.x, d = threadIdx.x;
    float v = X[(long)n*DD + d];
    red[d] = v; __syncthreads();
    for (int s=128; s>0; s>>=1){ if (d<s) red[d]+=red[d+s]; __syncthreads(); }
    float mu = red[0] * (1.0f/DD); __syncthreads();
    float df = v - mu;
    red[d] = df*df; __syncthreads();
    for (int s=128; s>0; s>>=1){ if (d<s) red[d]+=red[d+s]; __syncthreads(); }
    float var = red[0] * (1.0f/DD);
    float y = df*rsqrtf(var+1e-5f)*w[d] + b[d];
    Yb[(long)n*DD + d] = f2b(y);
    __syncthreads();
    red[d] = y * ow[d]; __syncthreads();
    for (int s=128; s>0; s>>=1){ if (d<s) red[d]+=red[d+s]; __syncthreads(); }
    if (d == 0) g[n] = red[0];
}

// ---------------- MFMA GEMM: C[N,M] = A[N,K](bf16) @ Wt[M,K](bf16)^T + bias ----------------
// mode 0: Cf = v ; mode 1: Cf += v ; mode 2: Cb = gelu(v) ; mode 3: Cb = v
__global__ __launch_bounds__(256) void k_mgemm(const bf16* __restrict__ A,
                                               const bf16* __restrict__ Wt,
                                               const float* __restrict__ bias,
                                               float* __restrict__ Cf,
                                               bf16* __restrict__ Cb,
                                               int K, int M, int mode){
    __shared__ short As[128*32];
    __shared__ short Ws[64*32];
    int tid = threadIdx.x;
    int lane = tid & 63, wv = tid >> 6;
    int n0 = blockIdx.y * 128, m0 = blockIdx.x * 64;
    int rbase = (wv >> 1) * 64, cbase = (wv & 1) * 32;
    f4v acc[4][2] = {};
    int s2 = tid + 256;
    for (int k0 = 0; k0 < K; k0 += 32){
        bf8v va0 = *(const bf8v*)(A  + (long)(n0 + (tid>>2))*K + k0 + ((tid&3)<<3));
        bf8v va1 = *(const bf8v*)(A  + (long)(n0 + (s2 >>2))*K + k0 + ((s2 &3)<<3));
        bf8v vw  = *(const bf8v*)(Wt + (long)(m0 + (tid>>2))*K + k0 + ((tid&3)<<3));
        __syncthreads();
        *(bf8v*)&As[tid*8] = va0;
        *(bf8v*)&As[s2 *8] = va1;
        *(bf8v*)&Ws[tid*8] = vw;
        __syncthreads();
        bf8v af[4], bfr[2];
        int k8 = (lane >> 4) << 3;
        #pragma unroll
        for (int i=0;i<4;i++) af[i]  = *(bf8v*)&As[(rbase + i*16 + (lane&15))*32 + k8];
        #pragma unroll
        for (int j=0;j<2;j++) bfr[j] = *(bf8v*)&Ws[(cbase + j*16 + (lane&15))*32 + k8];
        #pragma unroll
        for (int i=0;i<4;i++)
            #pragma unroll
            for (int j=0;j<2;j++)
                acc[i][j] = MFMA32(af[i], bfr[j], acc[i][j]);
    }
    int rq = (lane >> 4) * 4;
    int cl = lane & 15;
    #pragma unroll
    for (int i=0;i<4;i++){
        #pragma unroll
        for (int j=0;j<2;j++){
            int m = m0 + cbase + j*16 + cl;
            float bs = bias[m];
            #pragma unroll
            for (int r=0;r<4;r++){
                int n = n0 + rbase + i*16 + rq + r;
                float v = acc[i][j][r] + bs;
                long idx = (long)n*M + m;
                if (mode == 0)      Cf[idx] = v;
                else if (mode == 1) Cf[idx] += v;
                else if (mode == 2) Cb[idx] = f2b(0.5f*v*(1.0f + erff(v*0.70710678118654752f)));
                else                Cb[idx] = f2b(v);
            }
        }
    }
}

// ---------------- fused QKV GEMM + bias + RoPE + V tile-transpose ----------------
__global__ __launch_bounds__(256) void k_mgemmQKV(const bf16* __restrict__ A,
                                                  const bf16* __restrict__ Wt,
                                                  const float* __restrict__ bias,
                                                  const float* __restrict__ cosT,
                                                  const float* __restrict__ sinT,
                                                  bf16* __restrict__ qb,
                                                  bf16* __restrict__ kb,
                                                  bf16* __restrict__ vt){
    __shared__ short As[128*32];
    __shared__ short Ws[64*32];
    __shared__ short E[128][68];
    const int K = 256, M = 768;
    int tid = threadIdx.x;
    int lane = tid & 63, wv = tid >> 6;
    int n0 = blockIdx.y * 128, m0 = blockIdx.x * 64;
    int rbase = (wv >> 1) * 64, cbase = (wv & 1) * 32;
    f4v acc[4][2] = {};
    int s2 = tid + 256;
    for (int k0 = 0; k0 < K; k0 += 32){
        bf8v va0 = *(const bf8v*)(A  + (long)(n0 + (tid>>2))*K + k0 + ((tid&3)<<3));
        bf8v va1 = *(const bf8v*)(A  + (long)(n0 + (s2 >>2))*K + k0 + ((s2 &3)<<3));
        bf8v vw  = *(const bf8v*)(Wt + (long)(m0 + (tid>>2))*K + k0 + ((tid&3)<<3));
        __syncthreads();
        *(bf8v*)&As[tid*8] = va0;
        *(bf8v*)&As[s2 *8] = va1;
        *(bf8v*)&Ws[tid*8] = vw;
        __syncthreads();
        bf8v af[4], bfr[2];
        int k8 = (lane >> 4) << 3;
        #pragma unroll
        for (int i=0;i<4;i++) af[i]  = *(bf8v*)&As[(rbase + i*16 + (lane&15))*32 + k8];
        #pragma unroll
        for (int j=0;j<2;j++) bfr[j] = *(bf8v*)&Ws[(cbase + j*16 + (lane&15))*32 + k8];
        #pragma unroll
        for (int i=0;i<4;i++)
            #pragma unroll
            for (int j=0;j<2;j++)
                acc[i][j] = MFMA32(af[i], bfr[j], acc[i][j]);
    }
    int rq = (lane >> 4) * 4;
    int cl = lane & 15;
    #pragma unroll
    for (int i=0;i<4;i++){
        #pragma unroll
        for (int j=0;j<2;j++){
            int cc = cbase + j*16 + cl;
            float bs = bias[m0 + cc];
            #pragma unroll
            for (int r=0;r<4;r++)
                E[rbase + i*16 + rq + r][cc] = f2bs(acc[i][j][r] + bs);
        }
    }
    __syncthreads();
    int part = m0 >> 8;
    int h = (m0 >> 6) & 3;
    int b = n0 >> 11;
    int t0 = n0 & 2047;
    int bh = b*HH + h;
    if (part < 2){
        bf16* dst0 = part ? kb : qb;
        int r2 = tid >> 2;
        int c0 = (tid & 3) * 16;
        int cpx = c0 ^ 32;
        #pragma unroll
        for (int half=0; half<2; half++){
            int row = half*64 + r2;
            int t = t0 + row;
            bf8v e0 = *(bf8v*)&E[row][c0];
            bf8v e1 = *(bf8v*)&E[row][c0+8];
            bf8v p0 = *(bf8v*)&E[row][cpx];
            bf8v p1 = *(bf8v*)&E[row][cpx+8];
            const float* ct = cosT + t*32;
            const float* st = sinT + t*32;
            short o[16];
            #pragma unroll
            for (int i=0;i<8;i++){
                int d = c0 + i, dd = d & 31;
                float cs = ct[dd], sn = st[dd];
                float v = bs2f(e0[i]), v2 = bs2f(p0[i]);
                o[i] = f2bs((d < 32) ? (v*cs - v2*sn) : (v*cs + v2*sn));
            }
            #pragma unroll
            for (int i=0;i<8;i++){
                int d = c0 + 8 + i, dd = d & 31;
                float cs = ct[dd], sn = st[dd];
                float v = bs2f(e1[i]), v2 = bs2f(p1[i]);
                o[8+i] = f2bs((d < 32) ? (v*cs - v2*sn) : (v*cs + v2*sn));
            }
            short* dp = (short*)dst0 + ((long)bh*TT + t)*64 + c0;
            *(bf8v*)dp     = *(bf8v*)&o[0];
            *(bf8v*)(dp+8) = *(bf8v*)&o[8];
        }
    } else {
        int tIdx0 = t0 >> 6;
        int d  = (tid & 127) >> 1;
        int k0 = (tid & 1) * 32;
        int tt = tid >> 7;
        short o[32];
        #pragma unroll
        for (int k=0;k<32;k++) o[k] = E[tt*64 + k0 + k][d];
        short* dp = (short*)vt + (((long)bh*32 + tIdx0 + tt)*64 + d)*64 + k0;
        *(bf8v*)dp      = *(bf8v*)&o[0];
        *(bf8v*)(dp+8)  = *(bf8v*)&o[8];
        *(bf8v*)(dp+16) = *(bf8v*)&o[16];
        *(bf8v*)(dp+24) = *(bf8v*)&o[24];
    }
}

// ---------------- MFMA flash causal attention, double-buffered LDS + prefetch ----------------
// (single-pass; split-K rejected 3x: R9 181us, R19 +14us vs this structure)
__global__ __launch_bounds__(256) void k_fattn(const bf16* __restrict__ qb,
                                               const bf16* __restrict__ kb,
                                               const bf16* __restrict__ vt,
                                               bf16* __restrict__ ob){
    __shared__ short Ks[2][64][72];
    __shared__ short Vs[2][64][68];
    int bh = blockIdx.y;
    int qt = (int)(gridDim.x - 1) - (int)blockIdx.x;  // heavy tiles first
    int tid = threadIdx.x;
    int lane = tid & 63, w = tid >> 6;
    int col = lane & 15, quad = lane >> 4;
    int q0 = qt*64 + w*16;
    const bf16* qp = qb + ((long)bh*TT + q0 + col)*64 + quad*8;
    bf8v bq0 = *(const bf8v*)(qp);
    bf8v bq1 = *(const bf8v*)(qp + 32);
    f4v oc[4] = {};
    float lsum = 0.f;
    int qglob = q0 + col;
    int srow = tid >> 2, sc0 = (tid & 3) * 16;
    const short* kgb = (const short*)kb + ((long)bh*TT + srow)*64 + sc0;
    const short* vgb = (const short*)vt + (((long)bh*32)*64 + srow)*64 + sc0;

    bf8v pk0 = *(const bf8v*)kgb;
    bf8v pk1 = *(const bf8v*)(kgb + 8);
    bf8v pv0 = *(const bf8v*)vgb;
    bf8v pv1 = *(const bf8v*)(vgb + 8);
    *(bf8v*)&Ks[0][srow][sc0]     = pk0;
    *(bf8v*)&Ks[0][srow][sc0 + 8] = pk1;
    *(bf8v*)&Vs[0][srow][sc0]     = pv0;
    *(bf8v*)&Vs[0][srow][sc0 + 8] = pv1;

    int buf = 0;
    for (int kt=0; kt<=qt; kt++){
        __syncthreads();
        bool more = (kt < qt);
        if (more){
            const short* kg = kgb + (long)(kt+1)*4096;
            const short* vg = vgb + (long)(kt+1)*4096;
            pk0 = *(const bf8v*)kg;
            pk1 = *(const bf8v*)(kg + 8);
            pv0 = *(const bf8v*)vg;
            pv1 = *(const bf8v*)(vg + 8);
        }
        bool diag = (kt == qt);
        int ntmax = diag ? w : 3;
        bf4v bp[4];
        #pragma unroll
        for (int nt=0; nt<4; nt++){
            if (nt > ntmax) continue;
            bf8v ka0 = *(const bf8v*)&Ks[buf][nt*16 + col][quad*8];
            bf8v ka1 = *(const bf8v*)&Ks[buf][nt*16 + col][32 + quad*8];
            f4v st = {};
            st = MFMA32(ka0, bq0, st);
            st = MFMA32(ka1, bq1, st);
            int key0 = kt*64 + nt*16 + quad*4;
            bf4v pb;
            #pragma unroll
            for (int r=0; r<4; r++){
                float e = __expf(st[r]*0.125f);
                if (diag && (key0 + r > qglob)) e = 0.f;
                lsum += e;
                pb[r] = f2bs(e);
            }
            bp[nt] = pb;
        }
        #pragma unroll
        for (int dt=0; dt<4; dt++){
            #pragma unroll
            for (int nt=0; nt<4; nt++){
                if (nt > ntmax) continue;
                bf4v va = *(const bf4v*)&Vs[buf][dt*16 + col][nt*16 + quad*4];
                oc[dt] = MFMA16(va, bp[nt], oc[dt]);
            }
        }
        if (more){
            *(bf8v*)&Ks[buf^1][srow][sc0]     = pk0;
            *(bf8v*)&Ks[buf^1][srow][sc0 + 8] = pk1;
            *(bf8v*)&Vs[buf^1][srow][sc0]     = pv0;
            *(bf8v*)&Vs[buf^1][srow][sc0 + 8] = pv1;
        }
        buf ^= 1;
    }
    lsum += __shfl_xor(lsum, 16, 64);
    lsum += __shfl_xor(lsum, 32, 64);
    float linv = 1.0f / lsum;

    int b = bh / HH, h = bh % HH;
    long obase = ((long)b*TT + q0 + col)*DD + h*64 + quad*4;
    #pragma unroll
    for (int dt=0; dt<4; dt++){
        bf4v o4;
        #pragma unroll
        for (int r=0; r<4; r++) o4[r] = f2bs(oc[dt][r]*linv);
        *(bf4v*)(ob + obase + dt*16) = o4;
    }
}

// ---------------- pooling scores: S[b][q][t] = (oq[q] . xf[b,t]) / 16, MFMA ----------------
__global__ __launch_bounds__(256) void k_score(const bf16* __restrict__ oqb,
                                               const bf16* __restrict__ xfb,
                                               float* __restrict__ S){
    int b = blockIdx.y, t0 = blockIdx.x*64;
    int tid = threadIdx.x, lane = tid & 63, w = tid >> 6;
    int col = lane & 15, quad = lane >> 4, k8 = quad << 3;
    const bf16* xb = xfb + (long)b*TT*DD;
    f4v acc[2][4] = {};
    #pragma unroll
    for (int ko=0; ko<8; ko++){
        int kk = ko*32 + k8;
        bf8v a0 = *(const bf8v*)(oqb + (long)(w*32 +      col)*DD + kk);
        bf8v a1 = *(const bf8v*)(oqb + (long)(w*32 + 16 + col)*DD + kk);
        #pragma unroll
        for (int bt=0; bt<4; bt++){
            bf8v bv = *(const bf8v*)(xb + (long)(t0 + bt*16 + col)*DD + kk);
            acc[0][bt] = MFMA32(a0, bv, acc[0][bt]);
            acc[1][bt] = MFMA32(a1, bv, acc[1][bt]);
        }
    }
    #pragma unroll
    for (int qt2=0; qt2<2; qt2++){
        #pragma unroll
        for (int bt=0; bt<4; bt++){
            #pragma unroll
            for (int r=0; r<4; r++){
                int q = w*32 + qt2*16 + quad*4 + r;
                S[((long)b*NQ + q)*TT + t0 + bt*16 + col] = acc[qt2][bt][r]*0.0625f;
            }
        }
    }
}

// ---------------- softmax row + fused bit: one (b,q) per block ----------------
__global__ __launch_bounds__(256) void k_psoft(const float* __restrict__ S,
                                               const float* __restrict__ g,
                                               const float* __restrict__ obias,
                                               float* __restrict__ out_qattn,
                                               float* __restrict__ out_pairs,
                                               float* __restrict__ bits){
    __shared__ float p[TT];
    __shared__ float red[256];
    int bq = blockIdx.x, b = bq >> 7;
    int tid = threadIdx.x;
    const float* Srow = S + (long)bq*TT;
    float lmax = -1e30f;
    for (int t=tid; t<TT; t+=256){ float s = Srow[t]; p[t] = s; lmax = fmaxf(lmax, s); }
    red[tid] = lmax; __syncthreads();
    for (int s2=128; s2>0; s2>>=1){ if (tid<s2) red[tid]=fmaxf(red[tid],red[tid+s2]); __syncthreads(); }
    float m = red[0]; __syncthreads();
    const float* gb = g + (long)b*TT;
    float lsum = 0.f, gdot = 0.f;
    for (int t=tid; t<TT; t+=256){
        float e = __expf(p[t]-m); p[t] = e;
        lsum += e; gdot += e*gb[t];
    }
    red[tid] = lsum; __syncthreads();
    for (int s2=128; s2>0; s2>>=1){ if (tid<s2) red[tid]+=red[tid+s2]; __syncthreads(); }
    float inv = 1.0f/red[0]; __syncthreads();
    red[tid] = gdot; __syncthreads();
    for (int s2=128; s2>0; s2>>=1){ if (tid<s2) red[tid]+=red[tid+s2]; __syncthreads(); }
    float gsum = red[0];
    for (int t=tid; t<TT; t+=256) out_qattn[(long)bq*TT + t] = p[t]*inv;
    if (tid == 0){
        float bit = 1.0f/(1.0f + expf(-(gsum*inv + obias[0])));
        bits[bq] = bit;
        out_pairs[bq] = bit;
    }
}

// ---------------- sequential 64-step carry MLP (structural floor ~51 us) ----------------
__global__ __launch_bounds__(64) void k_scan(const float* __restrict__ bits,
                                             const float* __restrict__ w1, const float* __restrict__ b1,
                                             const float* __restrict__ w2t, const float* __restrict__ b2,
                                             const float* __restrict__ w3, const float* __restrict__ b3,
                                             float* __restrict__ out_sum){
    int b = blockIdx.x, lane = threadIdx.x;
    float w1c0 = w1[lane], w1c1 = w1[64 + lane], w1c2 = w1[128 + lane];
    float b1v = b1[lane], b2v = b2[lane];
    float w3c0 = w3[lane*2 + 0], w3c1 = w3[lane*2 + 1];
    float b30 = b3[0], b31 = b3[1];
    const f4v* wrow = (const f4v*)(w2t + (long)lane*64);
    f4v c0v = wrow[0],  c1v = wrow[1],  c2v = wrow[2],  c3v = wrow[3],
        c4v = wrow[4],  c5v = wrow[5],  c6v = wrow[6],  c7v = wrow[7],
        c8v = wrow[8],  c9v = wrow[9],  cav = wrow[10], cbv = wrow[11],
        ccv = wrow[12], cdv = wrow[13], cev = wrow[14], cfv = wrow[15];
    float z0v = bits[b*128 + lane*2 + 0];
    float z1v = bits[b*128 + lane*2 + 1];
    float carry = 0.f;
    for (int step=0; step<64; step++){
        float z0 = rl(z0v, step);
        float z1 = rl(z1v, step);
        float h1 = fmaxf(z0*w1c0 + z1*w1c1 + carry*w1c2 + b1v, 0.f);
        float a0 = b2v, a1 = 0.f, a2 = 0.f, a3 = 0.f;
#define MAC(i, c) { a0 += rl(h1, 4*i+0) * c[0]; a1 += rl(h1, 4*i+1) * c[1]; \
                    a2 += rl(h1, 4*i+2) * c[2]; a3 += rl(h1, 4*i+3) * c[3]; }
        MAC(0,c0v)  MAC(1,c1v)  MAC(2,c2v)  MAC(3,c3v)
        MAC(4,c4v)  MAC(5,c5v)  MAC(6,c6v)  MAC(7,c7v)
        MAC(8,c8v)  MAC(9,c9v)  MAC(10,cav) MAC(11,cbv)
        MAC(12,ccv) MAC(13,cdv) MAC(14,cev) MAC(15,cfv)
#undef MAC
        float h2 = fmaxf((a0+a1)+(a2+a3), 0.f);
        float t0 = h2*w3c0, t1 = h2*w3c1;
        #pragma unroll
        for (int m=1; m<64; m<<=1){
            t0 += __shfl_xor(t0, m, 64);
            t1 += __shfl_xor(t1, m, 64);
        }
        float o0 = 1.0f/(1.0f + __expf(-(t0 + b30)));
        carry    = 1.0f/(1.0f + __expf(-(t1 + b31)));
        if (lane == 0) out_sum[b*65 + step] = o0;
    }
    if (lane == 0) out_sum[b*65 + 64] = carry;
}

extern "C" void kernel_launch(void* const* d_in, const int* in_sizes, int n_in,
                              void* d_out, int out_size, void* d_ws, size_t ws_size,
                              hipStream_t stream){
    const int*   tok   = (const int*)d_in[0];
    const float* emb   = (const float*)d_in[1];
    const float* ln1w  = (const float*)d_in[2];
    const float* ln1b  = (const float*)d_in[3];
    const float* qkvw  = (const float*)d_in[4];
    const float* qkvb  = (const float*)d_in[5];
    const float* projw = (const float*)d_in[6];
    const float* projb = (const float*)d_in[7];
    const float* ln2w  = (const float*)d_in[8];
    const float* ln2b  = (const float*)d_in[9];
    const float* f1w   = (const float*)d_in[10];
    const float* f1b   = (const float*)d_in[11];
    const float* f2w   = (const float*)d_in[12];
    const float* f2bb  = (const float*)d_in[13];
    const float* lnfw  = (const float*)d_in[14];
    const float* lnfb  = (const float*)d_in[15];
    const float* oq    = (const float*)d_in[16];
    const float* ow    = (const float*)d_in[17];
    const float* obias = (const float*)d_in[18];
    const float* w1    = (const float*)d_in[19];
    const float* b1    = (const float*)d_in[20];
    const float* w2    = (const float*)d_in[21];
    const float* b2    = (const float*)d_in[22];
    const float* w3    = (const float*)d_in[23];
    const float* b3    = (const float*)d_in[24];
    float* out = (float*)d_out;

    const long MB = 1048576;
    char* W = (char*)d_ws;
    float* x     = (float*)(W);            // [0,8M) residual fp32
    bf16*  attnb = (bf16*)(W + 8*MB);      // [8M,12M)
    bf16*  hb    = (bf16*)(W + 16*MB);     // [16M,32M) FFN hidden bf16
    bf16*  qb    = (bf16*)(W + 32*MB);     // [32M,36M)
    bf16*  kb    = (bf16*)(W + 36*MB);     // [36M,40M)
    bf16*  vt    = (bf16*)(W + 44*MB);     // [44M,48M) V tile-blocked [bh][kt][d][k]
    bf16*  xnb   = (bf16*)(W + 48*MB);     // [48M,52M) LN out bf16
    bf16*  wt    = (bf16*)(W + 52*MB);     // [52M,55M) weights bf16 K-major
    float* bits  = (float*)(W + 55*MB);    // 2 KB
    bf16*  oqb   = (bf16*)(W + 56*MB);     // 64 KB
    float* cosT  = (float*)(W + 57*MB);    // 256 KB
    float* sinT  = cosT + 65536;           // 256 KB
    float* w2t   = (float*)(W + 58*MB);    // 16 KB
    bf16*  xfb   = (bf16*)(W + 32*MB);     // final LN bf16 (aliases dead qb)
    float* g     = (float*)(W + 36*MB);    // 32 KB (aliases dead kb)
    float* S     = (float*)(W + 40*MB);    // [40M,44M) scores fp32
    // wt per-layer offsets (bf16 elems), layer stride 786432:
    //   qkvT +0 | projT +196608 | f1T +262144 | f2T +524288

    k_wtall<<<dim3(32, 32, 8), dim3(32,8), 0, stream>>>(qkvw, projw, f1w, f2w, wt);
    k_misc<<<256, 256, 0, stream>>>(oq, oqb, cosT, sinT, w2, w2t);

    k_embln<<<NROW, 256, 0, stream>>>(tok, emb, ln1w, ln1b, x, xnb);
    for (int l=0; l<2; l++){
        long L = (long)l*786432;
        if (l) k_lnb<<<NROW, 256, 0, stream>>>(x, ln1w + l*DD, ln1b + l*DD, xnb);
        k_mgemmQKV<<<dim3(768/64, 64), 256, 0, stream>>>(
            xnb, wt + L, qkvb + l*768, cosT, sinT, qb, kb, vt);
        k_fattn<<<dim3(TT/64, BB*HH), 256, 0, stream>>>(qb, kb, vt, attnb);
        k_mgemm<<<dim3(256/64, 64), 256, 0, stream>>>(
            attnb, wt + L + 196608, projb + l*DD, x, (bf16*)0, 256, 256, 1);
        k_lnb<<<NROW, 256, 0, stream>>>(x, ln2w + l*DD, ln2b + l*DD, xnb);
        k_mgemm<<<dim3(1024/64, 64), 256, 0, stream>>>(
            xnb, wt + L + 262144, f1b + l*1024, (float*)0, hb, 256, 1024, 2);
        k_mgemm<<<dim3(256/64, 64), 256, 0, stream>>>(
            hb, wt + L + 524288, f2bb + l*DD, x, (bf16*)0, 1024, 256, 1);
    }
    k_lnf<<<NROW, 256, 0, stream>>>(x, lnfw, lnfb, ow, xfb, g);
    // outputs: sum_all [0,260) | pairs [260,772) | q_attn [772, 772+4*128*2048)
    k_score<<<dim3(TT/64, BB), 256, 0, stream>>>(oqb, xfb, S);
    k_psoft<<<BB*NQ, 256, 0, stream>>>(S, g, obias, out + 772, out + 260, bits);
    k_scan<<<4, 64, 0, stream>>>(bits, w1, b1, w2t, b2, w3, b3, out);
}